// Round 1
// baseline (185.136 us; speedup 1.0000x reference)
//
#include <hip/hip_runtime.h>

#define GAMMA_F 1.1f
#define F_DIM 5

// One block per box. Scan points in index order, chunk = BLOCK points.
// Block-wide stable prefix-sum over the in-radius mask gives each selected
// point its output slot; early-exit once S points found. Tail is zeroed
// (harness poisons d_out and does not re-poison between replays).
template <int BLOCK>
__global__ void __launch_bounds__(BLOCK) voxel_sampler_kernel(
    const float* __restrict__ pts,    // [N,5]
    const float* __restrict__ boxes,  // [B,7]
    float* __restrict__ out,          // [B,S,5]
    int N, int S) {
  constexpr int NW = BLOCK / 64;
  const int b = blockIdx.x;
  const int tid = threadIdx.x;
  const int lane = tid & 63;
  const int wid = tid >> 6;

  // Radius, bit-matching numpy: sqrt((dx*0.5)^2+(dy*0.5)^2) * 1.1, all f32,
  // no FMA contraction (use explicit _rn intrinsics).
  const float cx = boxes[b * 7 + 0];
  const float cy = boxes[b * 7 + 1];
  const float hdx = __fmul_rn(boxes[b * 7 + 3], 0.5f);
  const float hdy = __fmul_rn(boxes[b * 7 + 4], 0.5f);
  const float r = __fmul_rn(
      __fsqrt_rn(__fadd_rn(__fmul_rn(hdx, hdx), __fmul_rn(hdy, hdy))),
      GAMMA_F);

  __shared__ int s_wsum[NW];
  __shared__ int s_count;
  if (tid == 0) s_count = 0;
  __syncthreads();

  float* outb = out + (size_t)b * S * F_DIM;

  for (int base = 0; base < N; base += BLOCK) {
    const int i = base + tid;
    bool sel = false;
    float x = 0.0f, y = 0.0f;
    if (i < N) {
      x = pts[i * F_DIM + 0];
      y = pts[i * F_DIM + 1];
      const float ddx = __fsub_rn(x, cx);
      const float ddy = __fsub_rn(y, cy);
      const float dis =
          __fsqrt_rn(__fadd_rn(__fmul_rn(ddx, ddx), __fmul_rn(ddy, ddy)));
      sel = (dis <= r);
    }

    const unsigned long long m = __ballot(sel);
    if (lane == 0) s_wsum[wid] = __popcll(m);
    __syncthreads();

    const int cbase = s_count;
    int wbase = 0;
    int tot = 0;
#pragma unroll
    for (int w = 0; w < NW; ++w) {
      const int v = s_wsum[w];
      if (w < wid) wbase += v;
      tot += v;
    }

    const int pos =
        cbase + wbase + __popcll(m & ((1ULL << lane) - 1ULL));
    if (sel && pos < S) {
      float* o = outb + pos * F_DIM;
      o[0] = x;
      o[1] = y;
      o[2] = pts[i * F_DIM + 2];
      o[3] = pts[i * F_DIM + 3];
      o[4] = pts[i * F_DIM + 4];
    }
    __syncthreads();
    if (tid == 0) s_count = cbase + tot;
    __syncthreads();
    if (cbase + tot >= S) break;  // uniform: cbase/tot identical across block
  }

  __syncthreads();
  int cnt = s_count;
  if (cnt > S) cnt = S;
  // Zero the unfilled tail slots.
  for (int j = cnt * F_DIM + tid; j < S * F_DIM; j += BLOCK) outb[j] = 0.0f;
}

extern "C" void kernel_launch(void* const* d_in, const int* in_sizes, int n_in,
                              void* d_out, int out_size, void* d_ws,
                              size_t ws_size, hipStream_t stream) {
  const float* pts = (const float*)d_in[0];
  const float* boxes = (const float*)d_in[1];
  float* out = (float*)d_out;

  const int N = in_sizes[0] / F_DIM;  // 200000
  const int B = in_sizes[1] / 7;      // 256
  const int S = out_size / (B * F_DIM);  // 128

  voxel_sampler_kernel<1024><<<B, 1024, 0, stream>>>(pts, boxes, out, N, S);
}

// Round 2
// 56.107 us; speedup vs baseline: 3.2997x; 3.2997x over previous
//
#include <hip/hip_runtime.h>

#define GAMMA_F 1.1f
#define F_DIM 5

// ---------------- Phase 0: pack xy into contiguous float2[N] ----------------
__global__ void pack_xy_kernel(const float* __restrict__ pts,
                               float2* __restrict__ xy, int N) {
  const int i = blockIdx.x * blockDim.x + threadIdx.x;
  if (i < N) {
    float2 p;
    p.x = pts[i * F_DIM + 0];
    p.y = pts[i * F_DIM + 1];
    xy[i] = p;
  }
}

// ------- Phase 1: one wave per (box, segment), sync-free stable compaction ---
// Each wave scans its contiguous segment in index order, ballot+popc gives
// stable local slots; stores local offsets (ushort) of the first <=S hits.
// Early-exits once S hits found (wave-uniform). No __syncthreads anywhere.
template <int NWAVE>
__global__ void __launch_bounds__(NWAVE * 64) seg_compact_kernel(
    const float2* __restrict__ xy, const float* __restrict__ boxes,
    int* __restrict__ cnt, unsigned short* __restrict__ idx, int N, int S,
    int NSEG, int L) {
  const int lane = threadIdx.x & 63;
  const int wid = threadIdx.x >> 6;
  const int g = blockIdx.x * NWAVE + wid;  // global wave id = box*NSEG + seg
  const int box = g / NSEG;
  const int seg = g % NSEG;

  // Radius, bit-matching numpy (explicit _rn: no FMA contraction, IEEE sqrt).
  const float cx = boxes[box * 7 + 0];
  const float cy = boxes[box * 7 + 1];
  const float hdx = __fmul_rn(boxes[box * 7 + 3], 0.5f);
  const float hdy = __fmul_rn(boxes[box * 7 + 4], 0.5f);
  const float r = __fmul_rn(
      __fsqrt_rn(__fadd_rn(__fmul_rn(hdx, hdx), __fmul_rn(hdy, hdy))),
      GAMMA_F);

  const int start = seg * L;
  const int end = min(start + L, N);
  unsigned short* myidx = idx + (size_t)g * S;
  const unsigned long long ltmask = (1ULL << lane) - 1ULL;

  int c = 0;
  for (int i0 = start; i0 < end; i0 += 64) {
    const int i = i0 + lane;
    bool sel = false;
    if (i < end) {
      const float2 p = xy[i];
      const float ddx = __fsub_rn(p.x, cx);
      const float ddy = __fsub_rn(p.y, cy);
      const float dis =
          __fsqrt_rn(__fadd_rn(__fmul_rn(ddx, ddx), __fmul_rn(ddy, ddy)));
      sel = (dis <= r);
    }
    const unsigned long long m = __ballot(sel);
    const int pos = c + __popcll(m & ltmask);
    if (sel && pos < S) myidx[pos] = (unsigned short)(i - start);
    c += __popcll(m);
    if (c >= S) break;  // wave-uniform (c from ballot)
  }
  if (lane == 0) cnt[g] = min(c, S);
}

// ------- Phase 2: per box, prefix over segment counts + gather features ------
#define MAX_NSEG 64
__global__ void gather_kernel(const float* __restrict__ pts,
                              const int* __restrict__ cnt,
                              const unsigned short* __restrict__ idx,
                              float* __restrict__ out, int N, int S, int NSEG,
                              int L) {
  const int b = blockIdx.x;
  const int tid = threadIdx.x;  // blockDim.x == S
  __shared__ int scnt[MAX_NSEG];
  __shared__ int pfx[MAX_NSEG + 1];
  if (tid < NSEG) scnt[tid] = cnt[b * NSEG + tid];
  __syncthreads();
  if (tid == 0) {
    int acc = 0;
    for (int s = 0; s < NSEG; ++s) {
      pfx[s] = acc;
      acc += scnt[s];
    }
    pfx[NSEG] = acc;
  }
  __syncthreads();
  const int total = pfx[NSEG];
  float* o = out + ((size_t)b * S + tid) * F_DIM;
  if (tid < total) {
    // last s with pfx[s] <= tid (guaranteed cnt[s] > 0 for that s)
    int lo = 0, hi = NSEG - 1;
    while (lo < hi) {
      const int mid = (lo + hi + 1) >> 1;
      if (pfx[mid] <= tid) lo = mid;
      else hi = mid - 1;
    }
    const int s = lo;
    const int gi =
        s * L + (int)idx[((size_t)b * NSEG + s) * S + (tid - pfx[s])];
    const float* p = pts + (size_t)gi * F_DIM;
    o[0] = p[0];
    o[1] = p[1];
    o[2] = p[2];
    o[3] = p[3];
    o[4] = p[4];
  } else {
    o[0] = 0.0f;
    o[1] = 0.0f;
    o[2] = 0.0f;
    o[3] = 0.0f;
    o[4] = 0.0f;
  }
}

// ---------------- Fallback: proven R1 single-kernel version ----------------
template <int BLOCK>
__global__ void __launch_bounds__(BLOCK) voxel_sampler_fallback(
    const float* __restrict__ pts, const float* __restrict__ boxes,
    float* __restrict__ out, int N, int S) {
  constexpr int NW = BLOCK / 64;
  const int b = blockIdx.x;
  const int tid = threadIdx.x;
  const int lane = tid & 63;
  const int wid = tid >> 6;

  const float cx = boxes[b * 7 + 0];
  const float cy = boxes[b * 7 + 1];
  const float hdx = __fmul_rn(boxes[b * 7 + 3], 0.5f);
  const float hdy = __fmul_rn(boxes[b * 7 + 4], 0.5f);
  const float r = __fmul_rn(
      __fsqrt_rn(__fadd_rn(__fmul_rn(hdx, hdx), __fmul_rn(hdy, hdy))),
      GAMMA_F);

  __shared__ int s_wsum[NW];
  __shared__ int s_count;
  if (tid == 0) s_count = 0;
  __syncthreads();

  float* outb = out + (size_t)b * S * F_DIM;

  for (int base = 0; base < N; base += BLOCK) {
    const int i = base + tid;
    bool sel = false;
    float x = 0.0f, y = 0.0f;
    if (i < N) {
      x = pts[i * F_DIM + 0];
      y = pts[i * F_DIM + 1];
      const float ddx = __fsub_rn(x, cx);
      const float ddy = __fsub_rn(y, cy);
      const float dis =
          __fsqrt_rn(__fadd_rn(__fmul_rn(ddx, ddx), __fmul_rn(ddy, ddy)));
      sel = (dis <= r);
    }
    const unsigned long long m = __ballot(sel);
    if (lane == 0) s_wsum[wid] = __popcll(m);
    __syncthreads();
    const int cbase = s_count;
    int wbase = 0;
    int tot = 0;
#pragma unroll
    for (int w = 0; w < NW; ++w) {
      const int v = s_wsum[w];
      if (w < wid) wbase += v;
      tot += v;
    }
    const int pos = cbase + wbase + __popcll(m & ((1ULL << lane) - 1ULL));
    if (sel && pos < S) {
      float* o = outb + pos * F_DIM;
      o[0] = x;
      o[1] = y;
      o[2] = pts[i * F_DIM + 2];
      o[3] = pts[i * F_DIM + 3];
      o[4] = pts[i * F_DIM + 4];
    }
    __syncthreads();
    if (tid == 0) s_count = cbase + tot;
    __syncthreads();
    if (cbase + tot >= S) break;
  }

  __syncthreads();
  int cnt = s_count;
  if (cnt > S) cnt = S;
  for (int j = cnt * F_DIM + tid; j < S * F_DIM; j += BLOCK) outb[j] = 0.0f;
}

extern "C" void kernel_launch(void* const* d_in, const int* in_sizes, int n_in,
                              void* d_out, int out_size, void* d_ws,
                              size_t ws_size, hipStream_t stream) {
  const float* pts = (const float*)d_in[0];
  const float* boxes = (const float*)d_in[1];
  float* out = (float*)d_out;

  const int N = in_sizes[0] / F_DIM;     // 200000
  const int B = in_sizes[1] / 7;         // 256
  const int S = out_size / (B * F_DIM);  // 128

  const int NSEG = 64;
  const int L = (N + NSEG - 1) / NSEG;  // 3125

  const size_t sz_xy = (size_t)N * sizeof(float2);
  const size_t off_cnt = (sz_xy + 255) & ~(size_t)255;
  const size_t sz_cnt = (size_t)B * NSEG * sizeof(int);
  const size_t off_idx = (off_cnt + sz_cnt + 255) & ~(size_t)255;
  const size_t sz_idx = (size_t)B * NSEG * S * sizeof(unsigned short);
  const size_t need = off_idx + sz_idx;

  const bool fast = (ws_size >= need) && (L <= 65535) &&
                    ((B * NSEG) % 4 == 0) && (S <= 1024) && (NSEG <= MAX_NSEG);

  if (fast) {
    char* ws = (char*)d_ws;
    float2* xy = (float2*)ws;
    int* cnt = (int*)(ws + off_cnt);
    unsigned short* idx = (unsigned short*)(ws + off_idx);

    pack_xy_kernel<<<(N + 255) / 256, 256, 0, stream>>>(pts, xy, N);
    seg_compact_kernel<4><<<(B * NSEG) / 4, 256, 0, stream>>>(
        xy, boxes, cnt, idx, N, S, NSEG, L);
    gather_kernel<<<B, S, 0, stream>>>(pts, cnt, idx, out, N, S, NSEG, L);
  } else {
    voxel_sampler_fallback<1024><<<B, 1024, 0, stream>>>(pts, boxes, out, N,
                                                         S);
  }
}

// Round 3
// 34.543 us; speedup vs baseline: 5.3595x; 1.6243x over previous
//
#include <hip/hip_runtime.h>

#define GAMMA_F 1.1f
#define F_DIM 5
#define BOXG 8
#define MAX_NSEG 64

// ---------------- Phase 0: pack xy into contiguous float2[N] ----------------
__global__ void pack_xy_kernel(const float* __restrict__ pts,
                               float2* __restrict__ xy, int N) {
  const int i = blockIdx.x * blockDim.x + threadIdx.x;
  if (i < N) {
    float2 p;
    p.x = pts[i * F_DIM + 0];
    p.y = pts[i * F_DIM + 1];
    xy[i] = p;
  }
}

// ---- Phase 1: one wave per (segment, 8-box group); sqrt-free, sync-free ----
// Exact threshold: sel == (sqrt_rn(s) <= r) with s = fadd(fmul(dx,dx),
// fmul(dy,dy)). Largest admissible f32 s is derived in closed form:
// sqrt_rn(s) <= r  <=>  sqrt(s) < m  (or <= m if RN tie rounds to r), where
// m = midpoint(r, succ(r)) is exact in double and m^2 is exact in double.
// smax = largest f32 (<|<=) m^2. Inner loop: 6 VALU ops per test, no sqrt.
template <int NWAVE>
__global__ void __launch_bounds__(NWAVE * 64) seg_compact8_kernel(
    const float4* __restrict__ xy4, const float* __restrict__ boxes,
    int* __restrict__ cnt, unsigned short* __restrict__ idx, int N, int S,
    int NSEG, int L, int NGRP) {
  const int lane = threadIdx.x & 63;
  const int wid = threadIdx.x >> 6;
  const int g = blockIdx.x * NWAVE + wid;  // g = seg*NGRP + grp
  const int seg = g / NGRP;
  const int grp = g % NGRP;
  const int box0 = grp * BOXG;

  float cx[BOXG], cy[BOXG], smax[BOXG];
#pragma unroll
  for (int b = 0; b < BOXG; ++b) {
    const float* bx = boxes + (box0 + b) * 7;
    cx[b] = bx[0];
    cy[b] = bx[1];
    const float hdx = __fmul_rn(bx[3], 0.5f);
    const float hdy = __fmul_rn(bx[4], 0.5f);
    const float r = __fmul_rn(
        __fsqrt_rn(__fadd_rn(__fmul_rn(hdx, hdx), __fmul_rn(hdy, hdy))),
        GAMMA_F);
    const unsigned ru = __float_as_uint(r);
    const float rsucc = __uint_as_float(ru + 1u);  // r > 0, finite
    const double m = ((double)r + (double)rsucc) * 0.5;  // exact
    const double m2 = m * m;                             // exact (<=50 bits)
    const bool incl = ((ru & 1u) == 0u);  // tie-to-even lands on r
    const float c1 = (float)m2;
    const double c1d = (double)c1;
    const bool keep = incl ? (c1d <= m2) : (c1d < m2);
    smax[b] = keep ? c1 : __uint_as_float(__float_as_uint(c1) - 1u);
  }

  const int start = seg * L;  // L even -> float4-aligned
  const int end = min(start + L, N);
  const int npts = end - start;

  int c[BOXG];
#pragma unroll
  for (int b = 0; b < BOXG; ++b) c[b] = 0;

  const unsigned long long lt = (1ULL << lane) - 1ULL;
  const unsigned long long le = lt | (1ULL << lane);
  const size_t ibase = ((size_t)box0 * NSEG + seg) * S;
  const int base4 = start >> 1;

  const int nfull = (npts > 0) ? (npts / 128) : 0;
  for (int it = 0; it < nfull; ++it) {
    const float4 q = xy4[base4 + it * 64 + lane];
    const int rel = it * 128 + 2 * lane;
#pragma unroll
    for (int b = 0; b < BOXG; ++b) {
      const float dx0 = __fsub_rn(q.x, cx[b]);
      const float dy0 = __fsub_rn(q.y, cy[b]);
      const float s0 = __fadd_rn(__fmul_rn(dx0, dx0), __fmul_rn(dy0, dy0));
      const float dx1 = __fsub_rn(q.z, cx[b]);
      const float dy1 = __fsub_rn(q.w, cy[b]);
      const float s1 = __fadd_rn(__fmul_rn(dx1, dx1), __fmul_rn(dy1, dy1));
      const bool sel0 = (s0 <= smax[b]);
      const bool sel1 = (s1 <= smax[b]);
      const unsigned long long m0 = __ballot(sel0);
      const unsigned long long m1 = __ballot(sel1);
      if (m0 | m1) {  // rare (~15% of box-iters)
        const int r0 = c[b] + __popcll(m0 & lt) + __popcll(m1 & lt);
        const int r1 = c[b] + __popcll(m0 & le) + __popcll(m1 & lt);
        unsigned short* mp = idx + ibase + (size_t)b * NSEG * S;
        if (sel0 && r0 < S) mp[r0] = (unsigned short)rel;
        if (sel1 && r1 < S) mp[r1] = (unsigned short)(rel + 1);
        c[b] += __popcll(m0) + __popcll(m1);
      }
    }
  }

  // Tail (guarded)
  const int relb = nfull * 128;
  if (relb < npts) {
    const int rel = relb + 2 * lane;
    float4 q = make_float4(0.f, 0.f, 0.f, 0.f);
    if (rel < npts) q = xy4[base4 + nfull * 64 + lane];
#pragma unroll
    for (int b = 0; b < BOXG; ++b) {
      const float dx0 = __fsub_rn(q.x, cx[b]);
      const float dy0 = __fsub_rn(q.y, cy[b]);
      const float s0 = __fadd_rn(__fmul_rn(dx0, dx0), __fmul_rn(dy0, dy0));
      const float dx1 = __fsub_rn(q.z, cx[b]);
      const float dy1 = __fsub_rn(q.w, cy[b]);
      const float s1 = __fadd_rn(__fmul_rn(dx1, dx1), __fmul_rn(dy1, dy1));
      const bool sel0 = (rel < npts) && (s0 <= smax[b]);
      const bool sel1 = (rel + 1 < npts) && (s1 <= smax[b]);
      const unsigned long long m0 = __ballot(sel0);
      const unsigned long long m1 = __ballot(sel1);
      if (m0 | m1) {
        const int r0 = c[b] + __popcll(m0 & lt) + __popcll(m1 & lt);
        const int r1 = c[b] + __popcll(m0 & le) + __popcll(m1 & lt);
        unsigned short* mp = idx + ibase + (size_t)b * NSEG * S;
        if (sel0 && r0 < S) mp[r0] = (unsigned short)rel;
        if (sel1 && r1 < S) mp[r1] = (unsigned short)(rel + 1);
        c[b] += __popcll(m0) + __popcll(m1);
      }
    }
  }

  if (lane == 0) {
#pragma unroll
    for (int b = 0; b < BOXG; ++b)
      cnt[(box0 + b) * NSEG + seg] = min(c[b], S);
  }
}

// ------- Phase 2: per box, prefix over segment counts + gather features ------
__global__ void gather_kernel(const float* __restrict__ pts,
                              const int* __restrict__ cnt,
                              const unsigned short* __restrict__ idx,
                              float* __restrict__ out, int N, int S, int NSEG,
                              int L) {
  const int b = blockIdx.x;
  const int tid = threadIdx.x;  // blockDim.x == S
  __shared__ int pfx[MAX_NSEG + 1];
  __shared__ int scnt[MAX_NSEG];
  if (tid < NSEG) scnt[tid] = cnt[b * NSEG + tid];
  __syncthreads();
  if (tid == 0) {
    int acc = 0;
    for (int s = 0; s < NSEG; ++s) {
      pfx[s] = acc;
      acc += scnt[s];
    }
    pfx[NSEG] = acc;
  }
  __syncthreads();
  const int total = pfx[NSEG];
  float* o = out + ((size_t)b * S + tid) * F_DIM;
  if (tid < total) {
    int lo = 0, hi = NSEG - 1;
    while (lo < hi) {
      const int mid = (lo + hi + 1) >> 1;
      if (pfx[mid] <= tid) lo = mid;
      else hi = mid - 1;
    }
    const int s = lo;
    const int gi = s * L + (int)idx[((size_t)b * NSEG + s) * S + (tid - pfx[s])];
    const float* p = pts + (size_t)gi * F_DIM;
    o[0] = p[0];
    o[1] = p[1];
    o[2] = p[2];
    o[3] = p[3];
    o[4] = p[4];
  } else {
    o[0] = 0.0f;
    o[1] = 0.0f;
    o[2] = 0.0f;
    o[3] = 0.0f;
    o[4] = 0.0f;
  }
}

// ---------------- Fallback: proven R1 single-kernel version ----------------
template <int BLOCK>
__global__ void __launch_bounds__(BLOCK) voxel_sampler_fallback(
    const float* __restrict__ pts, const float* __restrict__ boxes,
    float* __restrict__ out, int N, int S) {
  constexpr int NW = BLOCK / 64;
  const int b = blockIdx.x;
  const int tid = threadIdx.x;
  const int lane = tid & 63;
  const int wid = tid >> 6;

  const float cx = boxes[b * 7 + 0];
  const float cy = boxes[b * 7 + 1];
  const float hdx = __fmul_rn(boxes[b * 7 + 3], 0.5f);
  const float hdy = __fmul_rn(boxes[b * 7 + 4], 0.5f);
  const float r = __fmul_rn(
      __fsqrt_rn(__fadd_rn(__fmul_rn(hdx, hdx), __fmul_rn(hdy, hdy))),
      GAMMA_F);

  __shared__ int s_wsum[NW];
  __shared__ int s_count;
  if (tid == 0) s_count = 0;
  __syncthreads();

  float* outb = out + (size_t)b * S * F_DIM;

  for (int base = 0; base < N; base += BLOCK) {
    const int i = base + tid;
    bool sel = false;
    float x = 0.0f, y = 0.0f;
    if (i < N) {
      x = pts[i * F_DIM + 0];
      y = pts[i * F_DIM + 1];
      const float ddx = __fsub_rn(x, cx);
      const float ddy = __fsub_rn(y, cy);
      const float dis =
          __fsqrt_rn(__fadd_rn(__fmul_rn(ddx, ddx), __fmul_rn(ddy, ddy)));
      sel = (dis <= r);
    }
    const unsigned long long m = __ballot(sel);
    if (lane == 0) s_wsum[wid] = __popcll(m);
    __syncthreads();
    const int cbase = s_count;
    int wbase = 0;
    int tot = 0;
#pragma unroll
    for (int w = 0; w < NW; ++w) {
      const int v = s_wsum[w];
      if (w < wid) wbase += v;
      tot += v;
    }
    const int pos = cbase + wbase + __popcll(m & ((1ULL << lane) - 1ULL));
    if (sel && pos < S) {
      float* o = outb + pos * F_DIM;
      o[0] = x;
      o[1] = y;
      o[2] = pts[i * F_DIM + 2];
      o[3] = pts[i * F_DIM + 3];
      o[4] = pts[i * F_DIM + 4];
    }
    __syncthreads();
    if (tid == 0) s_count = cbase + tot;
    __syncthreads();
    if (cbase + tot >= S) break;
  }

  __syncthreads();
  int cnt = s_count;
  if (cnt > S) cnt = S;
  for (int j = cnt * F_DIM + tid; j < S * F_DIM; j += BLOCK) outb[j] = 0.0f;
}

extern "C" void kernel_launch(void* const* d_in, const int* in_sizes, int n_in,
                              void* d_out, int out_size, void* d_ws,
                              size_t ws_size, hipStream_t stream) {
  const float* pts = (const float*)d_in[0];
  const float* boxes = (const float*)d_in[1];
  float* out = (float*)d_out;

  const int N = in_sizes[0] / F_DIM;     // 200000
  const int B = in_sizes[1] / 7;         // 256
  const int S = out_size / (B * F_DIM);  // 128

  const int NSEG = 64;
  int L = ((N + NSEG - 1) / NSEG + 1) & ~1;  // even -> float4-aligned segs
  const int NGRP = B / BOXG;
  constexpr int NWAVE = 4;

  const size_t sz_xy = (size_t)N * sizeof(float2);
  const size_t off_cnt = (sz_xy + 255) & ~(size_t)255;
  const size_t sz_cnt = (size_t)B * NSEG * sizeof(int);
  const size_t off_idx = (off_cnt + sz_cnt + 255) & ~(size_t)255;
  const size_t sz_idx = (size_t)B * NSEG * S * sizeof(unsigned short);
  const size_t need = off_idx + sz_idx + 256;  // +256: tail float4 overread pad

  const bool fast = (ws_size >= need) && (L <= 65534) && (B % BOXG == 0) &&
                    (S <= 1024) && (NSEG <= MAX_NSEG) && (N % 2 == 0) &&
                    ((NSEG * NGRP) % NWAVE == 0) && ((size_t)L * NSEG >= (size_t)N);

  if (fast) {
    char* ws = (char*)d_ws;
    float2* xy = (float2*)ws;
    int* cnt = (int*)(ws + off_cnt);
    unsigned short* idx = (unsigned short*)(ws + off_idx);

    pack_xy_kernel<<<(N + 255) / 256, 256, 0, stream>>>(pts, xy, N);
    seg_compact8_kernel<NWAVE>
        <<<(NSEG * NGRP) / NWAVE, NWAVE * 64, 0, stream>>>(
            (const float4*)xy, boxes, cnt, idx, N, S, NSEG, L, NGRP);
    gather_kernel<<<B, S, 0, stream>>>(pts, cnt, idx, out, N, S, NSEG, L);
  } else {
    voxel_sampler_fallback<1024><<<B, 1024, 0, stream>>>(pts, boxes, out, N,
                                                         S);
  }
}

// Round 4
// 27.731 us; speedup vs baseline: 6.6761x; 1.2457x over previous
//
#include <hip/hip_runtime.h>

#define GAMMA_F 1.1f
#define F_DIM 5
#define BOXG 8
#define MAX_NSEG 256

// ------- Phase 0: pack xy into float2[N] + per-box (cx,cy,smax) params ------
// smax: largest f32 s with sqrt_rn(s) <= r (exactness proven in R2/R3:
// midpoint m of [r, succ(r)] and m^2 are exact in double; tie direction from
// r's mantissa parity). Moves all sqrt/f64 work out of the hot seg kernel.
__global__ void pack_xy_boxes_kernel(const float* __restrict__ pts,
                                     const float* __restrict__ boxes,
                                     float2* __restrict__ xy,
                                     float4* __restrict__ bp, int N, int B) {
  if (blockIdx.x == gridDim.x - 1) {
    for (int b = threadIdx.x; b < B; b += blockDim.x) {
      const float* bx = boxes + b * 7;
      const float hdx = __fmul_rn(bx[3], 0.5f);
      const float hdy = __fmul_rn(bx[4], 0.5f);
      const float r = __fmul_rn(
          __fsqrt_rn(__fadd_rn(__fmul_rn(hdx, hdx), __fmul_rn(hdy, hdy))),
          GAMMA_F);
      const unsigned ru = __float_as_uint(r);
      const float rsucc = __uint_as_float(ru + 1u);      // r > 0, finite
      const double m = ((double)r + (double)rsucc) * 0.5;  // exact
      const double m2 = m * m;                             // exact
      const bool incl = ((ru & 1u) == 0u);  // RN tie-to-even lands on r
      const float c1 = (float)m2;
      const double c1d = (double)c1;
      const bool keep = incl ? (c1d <= m2) : (c1d < m2);
      const float smax =
          keep ? c1 : __uint_as_float(__float_as_uint(c1) - 1u);
      bp[b] = make_float4(bx[0], bx[1], smax, 0.0f);
    }
    return;
  }
  const int i = blockIdx.x * blockDim.x + threadIdx.x;
  if (i < N) {
    float2 p;
    p.x = pts[i * F_DIM + 0];
    p.y = pts[i * F_DIM + 1];
    xy[i] = p;
  }
}

// ---- Phase 1: one wave per (segment, 8-box group); sqrt-free, sync-free ----
template <int NWAVE>
__global__ void __launch_bounds__(NWAVE * 64) seg_compact8_kernel(
    const float4* __restrict__ xy4, const float4* __restrict__ bp,
    int* __restrict__ cnt, unsigned short* __restrict__ idx, int N, int S,
    int NSEG, int L, int NGRP) {
  const int lane = threadIdx.x & 63;
  const int wid = threadIdx.x >> 6;
  const int g = blockIdx.x * NWAVE + wid;  // g = seg*NGRP + grp
  const int seg = g / NGRP;
  const int grp = g % NGRP;
  const int box0 = grp * BOXG;

  float cx[BOXG], cy[BOXG], smax[BOXG];
#pragma unroll
  for (int b = 0; b < BOXG; ++b) {
    const float4 v = bp[box0 + b];
    cx[b] = v.x;
    cy[b] = v.y;
    smax[b] = v.z;
  }

  const int start = seg * L;  // L even -> float4-aligned
  const int end = min(start + L, N);
  const int npts = end - start;

  int c[BOXG];
#pragma unroll
  for (int b = 0; b < BOXG; ++b) c[b] = 0;

  const unsigned long long lt = (1ULL << lane) - 1ULL;
  const unsigned long long le = lt | (1ULL << lane);
  const size_t ibase = ((size_t)box0 * NSEG + seg) * S;
  const int base4 = start >> 1;

  const int nfull = (npts > 0) ? (npts / 128) : 0;
  for (int it = 0; it < nfull; ++it) {
    const float4 q = xy4[base4 + it * 64 + lane];
    const int rel = it * 128 + 2 * lane;
#pragma unroll
    for (int b = 0; b < BOXG; ++b) {
      const float dx0 = __fsub_rn(q.x, cx[b]);
      const float dy0 = __fsub_rn(q.y, cy[b]);
      const float s0 = __fadd_rn(__fmul_rn(dx0, dx0), __fmul_rn(dy0, dy0));
      const float dx1 = __fsub_rn(q.z, cx[b]);
      const float dy1 = __fsub_rn(q.w, cy[b]);
      const float s1 = __fadd_rn(__fmul_rn(dx1, dx1), __fmul_rn(dy1, dy1));
      const bool sel0 = (s0 <= smax[b]);
      const bool sel1 = (s1 <= smax[b]);
      const unsigned long long m0 = __ballot(sel0);
      const unsigned long long m1 = __ballot(sel1);
      if (m0 | m1) {  // rare
        const int r0 = c[b] + __popcll(m0 & lt) + __popcll(m1 & lt);
        const int r1 = c[b] + __popcll(m0 & le) + __popcll(m1 & lt);
        unsigned short* mp = idx + ibase + (size_t)b * NSEG * S;
        if (sel0 && r0 < S) mp[r0] = (unsigned short)rel;
        if (sel1 && r1 < S) mp[r1] = (unsigned short)(rel + 1);
        c[b] += __popcll(m0) + __popcll(m1);
      }
    }
  }

  // Tail (guarded; never reads past `end`)
  const int relb = nfull * 128;
  if (relb < npts) {
    const int rel = relb + 2 * lane;
    float4 q = make_float4(0.f, 0.f, 0.f, 0.f);
    if (rel < npts) q = xy4[base4 + nfull * 64 + lane];
#pragma unroll
    for (int b = 0; b < BOXG; ++b) {
      const float dx0 = __fsub_rn(q.x, cx[b]);
      const float dy0 = __fsub_rn(q.y, cy[b]);
      const float s0 = __fadd_rn(__fmul_rn(dx0, dx0), __fmul_rn(dy0, dy0));
      const float dx1 = __fsub_rn(q.z, cx[b]);
      const float dy1 = __fsub_rn(q.w, cy[b]);
      const float s1 = __fadd_rn(__fmul_rn(dx1, dx1), __fmul_rn(dy1, dy1));
      const bool sel0 = (rel < npts) && (s0 <= smax[b]);
      const bool sel1 = (rel + 1 < npts) && (s1 <= smax[b]);
      const unsigned long long m0 = __ballot(sel0);
      const unsigned long long m1 = __ballot(sel1);
      if (m0 | m1) {
        const int r0 = c[b] + __popcll(m0 & lt) + __popcll(m1 & lt);
        const int r1 = c[b] + __popcll(m0 & le) + __popcll(m1 & lt);
        unsigned short* mp = idx + ibase + (size_t)b * NSEG * S;
        if (sel0 && r0 < S) mp[r0] = (unsigned short)rel;
        if (sel1 && r1 < S) mp[r1] = (unsigned short)(rel + 1);
        c[b] += __popcll(m0) + __popcll(m1);
      }
    }
  }

  if (lane == 0) {
#pragma unroll
    for (int b = 0; b < BOXG; ++b) cnt[(box0 + b) * NSEG + seg] = min(c[b], S);
  }
}

// ------- Phase 2: per box, prefix over segment counts + gather features ------
// Block = 256 threads (4 waves). Shuffle-based wave scan + 2 barriers.
__global__ void __launch_bounds__(256) gather_kernel(
    const float* __restrict__ pts, const int* __restrict__ cnt,
    const unsigned short* __restrict__ idx, float* __restrict__ out, int N,
    int S, int NSEG, int L) {
  const int b = blockIdx.x;
  const int tid = threadIdx.x;
  const int lane = tid & 63;
  const int wid = tid >> 6;

  __shared__ int pfx[MAX_NSEG + 1];
  __shared__ int wtot[4];
  __shared__ int woff[4];

  int v = (tid < NSEG) ? cnt[b * NSEG + tid] : 0;
  int sv = v;
#pragma unroll
  for (int d = 1; d < 64; d <<= 1) {
    const int t = __shfl_up(sv, d, 64);
    if (lane >= d) sv += t;
  }
  if (lane == 63) wtot[wid] = sv;
  __syncthreads();
  if (tid == 0) {
    int a = 0;
#pragma unroll
    for (int w = 0; w < 4; ++w) {
      woff[w] = a;
      a += wtot[w];
    }
  }
  __syncthreads();
  const int incl = sv + woff[wid];
  if (tid < NSEG) pfx[tid + 1] = incl;
  if (tid == 0) pfx[0] = 0;
  __syncthreads();

  const int total = pfx[NSEG];
  if (tid < S) {
    float* o = out + ((size_t)b * S + tid) * F_DIM;
    if (tid < total) {
      int lo = 0, hi = NSEG - 1;
      while (lo < hi) {
        const int mid = (lo + hi + 1) >> 1;
        if (pfx[mid] <= tid) lo = mid;
        else hi = mid - 1;
      }
      const int s = lo;
      const int gi =
          s * L + (int)idx[((size_t)b * NSEG + s) * S + (tid - pfx[s])];
      const float* p = pts + (size_t)gi * F_DIM;
      o[0] = p[0];
      o[1] = p[1];
      o[2] = p[2];
      o[3] = p[3];
      o[4] = p[4];
    } else {
      o[0] = 0.0f;
      o[1] = 0.0f;
      o[2] = 0.0f;
      o[3] = 0.0f;
      o[4] = 0.0f;
    }
  }
}

// ---------------- Fallback: proven R1 single-kernel version ----------------
template <int BLOCK>
__global__ void __launch_bounds__(BLOCK) voxel_sampler_fallback(
    const float* __restrict__ pts, const float* __restrict__ boxes,
    float* __restrict__ out, int N, int S) {
  constexpr int NW = BLOCK / 64;
  const int b = blockIdx.x;
  const int tid = threadIdx.x;
  const int lane = tid & 63;
  const int wid = tid >> 6;

  const float cx = boxes[b * 7 + 0];
  const float cy = boxes[b * 7 + 1];
  const float hdx = __fmul_rn(boxes[b * 7 + 3], 0.5f);
  const float hdy = __fmul_rn(boxes[b * 7 + 4], 0.5f);
  const float r = __fmul_rn(
      __fsqrt_rn(__fadd_rn(__fmul_rn(hdx, hdx), __fmul_rn(hdy, hdy))),
      GAMMA_F);

  __shared__ int s_wsum[NW];
  __shared__ int s_count;
  if (tid == 0) s_count = 0;
  __syncthreads();

  float* outb = out + (size_t)b * S * F_DIM;

  for (int base = 0; base < N; base += BLOCK) {
    const int i = base + tid;
    bool sel = false;
    float x = 0.0f, y = 0.0f;
    if (i < N) {
      x = pts[i * F_DIM + 0];
      y = pts[i * F_DIM + 1];
      const float ddx = __fsub_rn(x, cx);
      const float ddy = __fsub_rn(y, cy);
      const float dis =
          __fsqrt_rn(__fadd_rn(__fmul_rn(ddx, ddx), __fmul_rn(ddy, ddy)));
      sel = (dis <= r);
    }
    const unsigned long long m = __ballot(sel);
    if (lane == 0) s_wsum[wid] = __popcll(m);
    __syncthreads();
    const int cbase = s_count;
    int wbase = 0;
    int tot = 0;
#pragma unroll
    for (int w = 0; w < NW; ++w) {
      const int v = s_wsum[w];
      if (w < wid) wbase += v;
      tot += v;
    }
    const int pos = cbase + wbase + __popcll(m & ((1ULL << lane) - 1ULL));
    if (sel && pos < S) {
      float* o = outb + pos * F_DIM;
      o[0] = x;
      o[1] = y;
      o[2] = pts[i * F_DIM + 2];
      o[3] = pts[i * F_DIM + 3];
      o[4] = pts[i * F_DIM + 4];
    }
    __syncthreads();
    if (tid == 0) s_count = cbase + tot;
    __syncthreads();
    if (cbase + tot >= S) break;
  }

  __syncthreads();
  int cnt = s_count;
  if (cnt > S) cnt = S;
  for (int j = cnt * F_DIM + tid; j < S * F_DIM; j += BLOCK) outb[j] = 0.0f;
}

extern "C" void kernel_launch(void* const* d_in, const int* in_sizes, int n_in,
                              void* d_out, int out_size, void* d_ws,
                              size_t ws_size, hipStream_t stream) {
  const float* pts = (const float*)d_in[0];
  const float* boxes = (const float*)d_in[1];
  float* out = (float*)d_out;

  const int N = in_sizes[0] / F_DIM;     // 200000
  const int B = in_sizes[1] / 7;         // 256
  const int S = out_size / (B * F_DIM);  // 128

  const int NSEG = 256;
  int L = ((N + NSEG - 1) / NSEG + 1) & ~1;  // even -> float4-aligned segs
  const int NGRP = B / BOXG;
  constexpr int NWAVE = 4;

  const size_t sz_xy = (size_t)N * sizeof(float2);
  const size_t off_cnt = (sz_xy + 255) & ~(size_t)255;
  const size_t sz_cnt = (size_t)B * NSEG * sizeof(int);
  const size_t off_idx = (off_cnt + sz_cnt + 255) & ~(size_t)255;
  const size_t sz_idx = (size_t)B * NSEG * S * sizeof(unsigned short);
  const size_t off_bp = (off_idx + sz_idx + 255) & ~(size_t)255;
  const size_t sz_bp = (size_t)B * sizeof(float4);
  const size_t need = off_bp + sz_bp;

  const bool fast = (ws_size >= need) && (L <= 65534) && (B % BOXG == 0) &&
                    (S <= 256) && (NSEG <= MAX_NSEG) && (N % 2 == 0) &&
                    ((NSEG * NGRP) % NWAVE == 0) &&
                    ((size_t)L * NSEG >= (size_t)N);

  if (fast) {
    char* ws = (char*)d_ws;
    float2* xy = (float2*)ws;
    int* cnt = (int*)(ws + off_cnt);
    unsigned short* idx = (unsigned short*)(ws + off_idx);
    float4* bpar = (float4*)(ws + off_bp);

    const int packb = (N + 255) / 256 + 1;  // last block computes box params
    pack_xy_boxes_kernel<<<packb, 256, 0, stream>>>(pts, boxes, xy, bpar, N,
                                                    B);
    seg_compact8_kernel<NWAVE>
        <<<(NSEG * NGRP) / NWAVE, NWAVE * 64, 0, stream>>>(
            (const float4*)xy, bpar, cnt, idx, N, S, NSEG, L, NGRP);
    gather_kernel<<<B, 256, 0, stream>>>(pts, cnt, idx, out, N, S, NSEG, L);
  } else {
    voxel_sampler_fallback<1024><<<B, 1024, 0, stream>>>(pts, boxes, out, N,
                                                         S);
  }
}

// Round 5
// 25.896 us; speedup vs baseline: 7.1491x; 1.0708x over previous
//
#include <hip/hip_runtime.h>

#define GAMMA_F 1.1f
#define F_DIM 5
#define BOXG 8
#define MAX_NSEG 256

__device__ __forceinline__ int prefix_lt(unsigned long long m) {
  // popcount(m & ((1<<lane)-1)) via mbcnt
  return __builtin_amdgcn_mbcnt_hi(
      (unsigned)(m >> 32), __builtin_amdgcn_mbcnt_lo((unsigned)m, 0u));
}

// ---- Phase 1: one wave per (segment, 8-box group); reads raw pts ----------
// Box threshold smax: largest f32 s with sqrt_rn(s) <= r (exactness proven in
// R2: midpoint m of [r,succ(r)] and m^2 exact in double; tie from r parity).
// Inner test: s = fadd_rn(fmul_rn(dx,dx), fmul_rn(dy,dy)) <= smax — bit-
// equivalent to reference sqrt compare.
template <int NWAVE>
__global__ void __launch_bounds__(NWAVE * 64) seg_compact8_kernel(
    const float* __restrict__ pts, const float* __restrict__ boxes,
    int* __restrict__ cnt, unsigned short* __restrict__ idx, int N, int S,
    int NSEG, int L, int NGRP) {
  const int lane = threadIdx.x & 63;
  const int wid = threadIdx.x >> 6;
  const int g = blockIdx.x * NWAVE + wid;  // g = seg*NGRP + grp
  const int seg = g / NGRP;
  const int grp = g - seg * NGRP;
  const int box0 = grp * BOXG;

  // Inline per-wave box params (uniform -> scalar loads).
  float cx[BOXG], cy[BOXG], smax[BOXG];
#pragma unroll
  for (int b = 0; b < BOXG; ++b) {
    const float* bx = boxes + (box0 + b) * 7;
    cx[b] = bx[0];
    cy[b] = bx[1];
    const float hdx = __fmul_rn(bx[3], 0.5f);
    const float hdy = __fmul_rn(bx[4], 0.5f);
    const float r = __fmul_rn(
        __fsqrt_rn(__fadd_rn(__fmul_rn(hdx, hdx), __fmul_rn(hdy, hdy))),
        GAMMA_F);
    const unsigned ru = __float_as_uint(r);
    const float rsucc = __uint_as_float(ru + 1u);        // r > 0, finite
    const double m = ((double)r + (double)rsucc) * 0.5;  // exact
    const double m2 = m * m;                             // exact
    const bool incl = ((ru & 1u) == 0u);  // RN tie-to-even lands on r
    const float c1 = (float)m2;
    const double c1d = (double)c1;
    const bool keep = incl ? (c1d <= m2) : (c1d < m2);
    smax[b] = keep ? c1 : __uint_as_float(__float_as_uint(c1) - 1u);
  }

  const int start = seg * L;
  const int end = min(start + L, N);
  const int npts = end - start;

  int c[BOXG];
#pragma unroll
  for (int b = 0; b < BOXG; ++b) c[b] = 0;

  const size_t ibase = ((size_t)box0 * NSEG + seg) * S;
  const int nfull = (npts > 0) ? (npts / 128) : 0;

  // lane handles points (start + it*128 + 2*lane, +1)
  const float* pp = pts + (size_t)(start + 2 * lane) * F_DIM;

#define PROCESS_8(RELBASE, X0, Y0, X1, Y1, G0, G1)                          \
  {                                                                         \
    const int rel = (RELBASE) + 2 * lane;                                   \
    _Pragma("unroll") for (int b = 0; b < BOXG; ++b) {                      \
      const float dx0 = __fsub_rn((X0), cx[b]);                             \
      const float dy0 = __fsub_rn((Y0), cy[b]);                             \
      const float s0 = __fadd_rn(__fmul_rn(dx0, dx0), __fmul_rn(dy0, dy0)); \
      const float dx1 = __fsub_rn((X1), cx[b]);                             \
      const float dy1 = __fsub_rn((Y1), cy[b]);                             \
      const float s1 = __fadd_rn(__fmul_rn(dx1, dx1), __fmul_rn(dy1, dy1)); \
      const bool sel0 = (G0) && (s0 <= smax[b]);                            \
      const bool sel1 = (G1) && (s1 <= smax[b]);                            \
      const unsigned long long m0 = __ballot(sel0);                         \
      const unsigned long long m1 = __ballot(sel1);                         \
      if (m0 | m1) {                                                        \
        const int p0 = prefix_lt(m0);                                       \
        const int p1 = prefix_lt(m1);                                       \
        const int r0 = c[b] + p0 + p1;                                      \
        const int r1 = c[b] + p0 + (sel0 ? 1 : 0) + p1;                     \
        unsigned short* mp = idx + ibase + (size_t)b * NSEG * S;            \
        if (sel0 && r0 < S) mp[r0] = (unsigned short)rel;                   \
        if (sel1 && r1 < S) mp[r1] = (unsigned short)(rel + 1);             \
        c[b] += __popcll(m0) + __popcll(m1);                                \
      }                                                                     \
    }                                                                       \
  }

  if (nfull > 0) {
    float x0 = pp[0], y0 = pp[1], x1 = pp[5], y1 = pp[6];
    for (int it = 0; it + 1 < nfull; ++it) {
      const float* pn = pp + 128 * F_DIM;
      const float nx0 = pn[0], ny0 = pn[1], nx1 = pn[5], ny1 = pn[6];
      PROCESS_8(it * 128, x0, y0, x1, y1, true, true);
      x0 = nx0;
      y0 = ny0;
      x1 = nx1;
      y1 = ny1;
      pp = pn;
    }
    PROCESS_8((nfull - 1) * 128, x0, y0, x1, y1, true, true);
    pp += 128 * F_DIM;
  }

  // Tail (guarded loads)
  const int relb = nfull * 128;
  if (relb < npts) {
    const int rel = relb + 2 * lane;
    float x0 = 0.f, y0 = 0.f, x1 = 0.f, y1 = 0.f;
    const bool g0 = (rel < npts);
    const bool g1 = (rel + 1 < npts);
    if (g0) {
      x0 = pp[0];
      y0 = pp[1];
    }
    if (g1) {
      x1 = pp[5];
      y1 = pp[6];
    }
    PROCESS_8(relb, x0, y0, x1, y1, g0, g1);
  }
#undef PROCESS_8

  if (lane == 0) {
#pragma unroll
    for (int b = 0; b < BOXG; ++b) cnt[(box0 + b) * NSEG + seg] = min(c[b], S);
  }
}

// ------- Phase 2: per box, prefix over segment counts + gather features ------
__global__ void __launch_bounds__(256) gather_kernel(
    const float* __restrict__ pts, const int* __restrict__ cnt,
    const unsigned short* __restrict__ idx, float* __restrict__ out, int N,
    int S, int NSEG, int L) {
  const int b = blockIdx.x;
  const int tid = threadIdx.x;
  const int lane = tid & 63;
  const int wid = tid >> 6;

  __shared__ int pfx[MAX_NSEG + 1];
  __shared__ int wtot[4];
  __shared__ int woff[4];

  int v = (tid < NSEG) ? cnt[b * NSEG + tid] : 0;
  int sv = v;
#pragma unroll
  for (int d = 1; d < 64; d <<= 1) {
    const int t = __shfl_up(sv, d, 64);
    if (lane >= d) sv += t;
  }
  if (lane == 63) wtot[wid] = sv;
  __syncthreads();
  if (tid == 0) {
    int a = 0;
#pragma unroll
    for (int w = 0; w < 4; ++w) {
      woff[w] = a;
      a += wtot[w];
    }
  }
  __syncthreads();
  const int incl = sv + woff[wid];
  if (tid < NSEG) pfx[tid + 1] = incl;
  if (tid == 0) pfx[0] = 0;
  __syncthreads();

  const int total = pfx[NSEG];
  if (tid < S) {
    float* o = out + ((size_t)b * S + tid) * F_DIM;
    if (tid < total) {
      int lo = 0, hi = NSEG - 1;
      while (lo < hi) {
        const int mid = (lo + hi + 1) >> 1;
        if (pfx[mid] <= tid) lo = mid;
        else hi = mid - 1;
      }
      const int s = lo;
      const int gi =
          s * L + (int)idx[((size_t)b * NSEG + s) * S + (tid - pfx[s])];
      const float* p = pts + (size_t)gi * F_DIM;
      o[0] = p[0];
      o[1] = p[1];
      o[2] = p[2];
      o[3] = p[3];
      o[4] = p[4];
    } else {
      o[0] = 0.0f;
      o[1] = 0.0f;
      o[2] = 0.0f;
      o[3] = 0.0f;
      o[4] = 0.0f;
    }
  }
}

// ---------------- Fallback: proven R1 single-kernel version ----------------
template <int BLOCK>
__global__ void __launch_bounds__(BLOCK) voxel_sampler_fallback(
    const float* __restrict__ pts, const float* __restrict__ boxes,
    float* __restrict__ out, int N, int S) {
  constexpr int NW = BLOCK / 64;
  const int b = blockIdx.x;
  const int tid = threadIdx.x;
  const int lane = tid & 63;
  const int wid = tid >> 6;

  const float cx = boxes[b * 7 + 0];
  const float cy = boxes[b * 7 + 1];
  const float hdx = __fmul_rn(boxes[b * 7 + 3], 0.5f);
  const float hdy = __fmul_rn(boxes[b * 7 + 4], 0.5f);
  const float r = __fmul_rn(
      __fsqrt_rn(__fadd_rn(__fmul_rn(hdx, hdx), __fmul_rn(hdy, hdy))),
      GAMMA_F);

  __shared__ int s_wsum[NW];
  __shared__ int s_count;
  if (tid == 0) s_count = 0;
  __syncthreads();

  float* outb = out + (size_t)b * S * F_DIM;

  for (int base = 0; base < N; base += BLOCK) {
    const int i = base + tid;
    bool sel = false;
    float x = 0.0f, y = 0.0f;
    if (i < N) {
      x = pts[i * F_DIM + 0];
      y = pts[i * F_DIM + 1];
      const float ddx = __fsub_rn(x, cx);
      const float ddy = __fsub_rn(y, cy);
      const float dis =
          __fsqrt_rn(__fadd_rn(__fmul_rn(ddx, ddx), __fmul_rn(ddy, ddy)));
      sel = (dis <= r);
    }
    const unsigned long long m = __ballot(sel);
    if (lane == 0) s_wsum[wid] = __popcll(m);
    __syncthreads();
    const int cbase = s_count;
    int wbase = 0;
    int tot = 0;
#pragma unroll
    for (int w = 0; w < NW; ++w) {
      const int v = s_wsum[w];
      if (w < wid) wbase += v;
      tot += v;
    }
    const int pos = cbase + wbase + __popcll(m & ((1ULL << lane) - 1ULL));
    if (sel && pos < S) {
      float* o = outb + pos * F_DIM;
      o[0] = x;
      o[1] = y;
      o[2] = pts[i * F_DIM + 2];
      o[3] = pts[i * F_DIM + 3];
      o[4] = pts[i * F_DIM + 4];
    }
    __syncthreads();
    if (tid == 0) s_count = cbase + tot;
    __syncthreads();
    if (cbase + tot >= S) break;
  }

  __syncthreads();
  int cnt = s_count;
  if (cnt > S) cnt = S;
  for (int j = cnt * F_DIM + tid; j < S * F_DIM; j += BLOCK) outb[j] = 0.0f;
}

extern "C" void kernel_launch(void* const* d_in, const int* in_sizes, int n_in,
                              void* d_out, int out_size, void* d_ws,
                              size_t ws_size, hipStream_t stream) {
  const float* pts = (const float*)d_in[0];
  const float* boxes = (const float*)d_in[1];
  float* out = (float*)d_out;

  const int N = in_sizes[0] / F_DIM;     // 200000
  const int B = in_sizes[1] / 7;         // 256
  const int S = out_size / (B * F_DIM);  // 128

  const int NSEG = 256;
  int L = ((N + NSEG - 1) / NSEG + 1) & ~1;  // even
  const int NGRP = B / BOXG;
  constexpr int NWAVE = 4;

  const size_t sz_cnt = (size_t)B * NSEG * sizeof(int);
  const size_t off_idx = (sz_cnt + 255) & ~(size_t)255;
  const size_t sz_idx = (size_t)B * NSEG * S * sizeof(unsigned short);
  const size_t need = off_idx + sz_idx;

  const bool fast = (ws_size >= need) && (L >= 2) && (L - 1 <= 65535) &&
                    (B % BOXG == 0) && (S <= 256) && (NSEG <= MAX_NSEG) &&
                    ((NSEG * NGRP) % NWAVE == 0) && (NWAVE <= NGRP) &&
                    ((size_t)L * NSEG >= (size_t)N);

  if (fast) {
    char* ws = (char*)d_ws;
    int* cnt = (int*)ws;
    unsigned short* idx = (unsigned short*)(ws + off_idx);

    seg_compact8_kernel<NWAVE>
        <<<(NSEG * NGRP) / NWAVE, NWAVE * 64, 0, stream>>>(
            pts, boxes, cnt, idx, N, S, NSEG, L, NGRP);
    gather_kernel<<<B, 256, 0, stream>>>(pts, cnt, idx, out, N, S, NSEG, L);
  } else {
    voxel_sampler_fallback<1024><<<B, 1024, 0, stream>>>(pts, boxes, out, N,
                                                         S);
  }
}

// Round 6
// 24.317 us; speedup vs baseline: 7.6133x; 1.0649x over previous
//
#include <hip/hip_runtime.h>

#define GAMMA_F 1.1f
#define F_DIM 5
#define BOXG 8
#define MAX_NSEG 256
#define MAXL 1024  // max points per segment staged in LDS (8 KB)

__device__ __forceinline__ int prefix_lt(unsigned long long m) {
  return __builtin_amdgcn_mbcnt_hi(
      (unsigned)(m >> 32), __builtin_amdgcn_mbcnt_lo((unsigned)m, 0u));
}

// ---- Phase 1: block = 1 segment x 8 box-groups; xy staged in LDS once. ----
// Box threshold smax: largest f32 s with sqrt_rn(s) <= r (exact, proven R2:
// midpoint m of [r,succ(r)] and m^2 exact in double; tie from r parity).
// Inner test s = fadd_rn(fmul_rn(dx,dx), fmul_rn(dy,dy)) <= smax is
// bit-equivalent to the reference sqrt compare.
template <int NWAVE>
__global__ void __launch_bounds__(NWAVE * 64, 4) seg_lds_kernel(
    const float* __restrict__ pts, const float* __restrict__ boxes,
    int* __restrict__ cnt, unsigned short* __restrict__ idx, int N, int S,
    int NSEG, int L, int NGRP) {
  __shared__ __align__(16) float2 sxy[MAXL];

  const int tid = threadIdx.x;
  const int lane = tid & 63;
  const int wid = tid >> 6;
  const int bpg = NGRP / NWAVE;  // blocks per segment
  const int seg = blockIdx.x / bpg;
  const int bg = blockIdx.x - seg * bpg;
  const int grp = bg * NWAVE + wid;
  const int box0 = grp * BOXG;

  const int start = seg * L;
  const int end = min(start + L, N);
  const int npts = end - start;

  // Per-wave box params (registers).
  float cx[BOXG], cy[BOXG], smax[BOXG];
#pragma unroll
  for (int b = 0; b < BOXG; ++b) {
    const float* bx = boxes + (box0 + b) * 7;
    cx[b] = bx[0];
    cy[b] = bx[1];
    const float hdx = __fmul_rn(bx[3], 0.5f);
    const float hdy = __fmul_rn(bx[4], 0.5f);
    const float r = __fmul_rn(
        __fsqrt_rn(__fadd_rn(__fmul_rn(hdx, hdx), __fmul_rn(hdy, hdy))),
        GAMMA_F);
    const unsigned ru = __float_as_uint(r);
    const float rsucc = __uint_as_float(ru + 1u);        // r > 0, finite
    const double m = ((double)r + (double)rsucc) * 0.5;  // exact
    const double m2 = m * m;                             // exact
    const bool incl = ((ru & 1u) == 0u);  // RN tie-to-even lands on r
    const float c1 = (float)m2;
    const double c1d = (double)c1;
    const bool keep = incl ? (c1d <= m2) : (c1d < m2);
    smax[b] = keep ? c1 : __uint_as_float(__float_as_uint(c1) - 1u);
  }

  // Stage this segment's xy into LDS (once per block).
  for (int t = tid; t < npts; t += NWAVE * 64) {
    const float* p = pts + (size_t)(start + t) * F_DIM;
    sxy[t] = make_float2(p[0], p[1]);
  }
  __syncthreads();

  int c[BOXG];
#pragma unroll
  for (int b = 0; b < BOXG; ++b) c[b] = 0;

  const size_t ibase = ((size_t)box0 * NSEG + seg) * S;
  const float4* sxy4 = (const float4*)sxy;

#define PROCESS_8(RELBASE, X0, Y0, X1, Y1, G0, G1)                          \
  {                                                                         \
    const int rel = (RELBASE) + 2 * lane;                                   \
    _Pragma("unroll") for (int b = 0; b < BOXG; ++b) {                      \
      const float dx0 = __fsub_rn((X0), cx[b]);                             \
      const float dy0 = __fsub_rn((Y0), cy[b]);                             \
      const float s0 = __fadd_rn(__fmul_rn(dx0, dx0), __fmul_rn(dy0, dy0)); \
      const float dx1 = __fsub_rn((X1), cx[b]);                             \
      const float dy1 = __fsub_rn((Y1), cy[b]);                             \
      const float s1 = __fadd_rn(__fmul_rn(dx1, dx1), __fmul_rn(dy1, dy1)); \
      const bool sel0 = (G0) && (s0 <= smax[b]);                            \
      const bool sel1 = (G1) && (s1 <= smax[b]);                            \
      const unsigned long long m0 = __ballot(sel0);                         \
      const unsigned long long m1 = __ballot(sel1);                         \
      if (m0 | m1) {                                                        \
        const int p0 = prefix_lt(m0);                                       \
        const int p1 = prefix_lt(m1);                                       \
        const int r0 = c[b] + p0 + p1;                                      \
        const int r1 = c[b] + p0 + (sel0 ? 1 : 0) + p1;                     \
        unsigned short* mp = idx + ibase + (size_t)b * NSEG * S;            \
        if (sel0 && r0 < S) mp[r0] = (unsigned short)rel;                   \
        if (sel1 && r1 < S) mp[r1] = (unsigned short)(rel + 1);             \
        c[b] += __popcll(m0) + __popcll(m1);                                \
      }                                                                     \
    }                                                                       \
  }

  const int nfull = npts / 128;
  for (int it = 0; it < nfull; ++it) {
    const float4 q = sxy4[it * 64 + lane];  // ds_read_b128, 2 points
    PROCESS_8(it * 128, q.x, q.y, q.z, q.w, true, true);
  }
  const int relb = nfull * 128;
  if (relb < npts) {
    const float4 q = sxy4[nfull * 64 + lane];  // in-bounds (MAXL), masked
    const int rel = relb + 2 * lane;
    const bool g0 = (rel < npts);
    const bool g1 = (rel + 1 < npts);
    PROCESS_8(relb, q.x, q.y, q.z, q.w, g0, g1);
  }
#undef PROCESS_8

  if (lane == 0) {
#pragma unroll
    for (int b = 0; b < BOXG; ++b) cnt[(box0 + b) * NSEG + seg] = min(c[b], S);
  }
}

// ------- Phase 2: per box, prefix over segment counts + gather features ------
__global__ void __launch_bounds__(256) gather_kernel(
    const float* __restrict__ pts, const int* __restrict__ cnt,
    const unsigned short* __restrict__ idx, float* __restrict__ out, int N,
    int S, int NSEG, int L) {
  const int b = blockIdx.x;
  const int tid = threadIdx.x;
  const int lane = tid & 63;
  const int wid = tid >> 6;

  __shared__ int pfx[MAX_NSEG + 1];
  __shared__ int wtot[4];
  __shared__ int woff[4];

  int v = (tid < NSEG) ? cnt[b * NSEG + tid] : 0;
  int sv = v;
#pragma unroll
  for (int d = 1; d < 64; d <<= 1) {
    const int t = __shfl_up(sv, d, 64);
    if (lane >= d) sv += t;
  }
  if (lane == 63) wtot[wid] = sv;
  __syncthreads();
  if (tid == 0) {
    int a = 0;
#pragma unroll
    for (int w = 0; w < 4; ++w) {
      woff[w] = a;
      a += wtot[w];
    }
  }
  __syncthreads();
  const int incl = sv + woff[wid];
  if (tid < NSEG) pfx[tid + 1] = incl;
  if (tid == 0) pfx[0] = 0;
  __syncthreads();

  const int total = pfx[NSEG];
  if (tid < S) {
    float* o = out + ((size_t)b * S + tid) * F_DIM;
    if (tid < total) {
      int lo = 0, hi = NSEG - 1;
      while (lo < hi) {
        const int mid = (lo + hi + 1) >> 1;
        if (pfx[mid] <= tid) lo = mid;
        else hi = mid - 1;
      }
      const int s = lo;
      const int gi =
          s * L + (int)idx[((size_t)b * NSEG + s) * S + (tid - pfx[s])];
      const float* p = pts + (size_t)gi * F_DIM;
      o[0] = p[0];
      o[1] = p[1];
      o[2] = p[2];
      o[3] = p[3];
      o[4] = p[4];
    } else {
      o[0] = 0.0f;
      o[1] = 0.0f;
      o[2] = 0.0f;
      o[3] = 0.0f;
      o[4] = 0.0f;
    }
  }
}

// ---------------- Fallback: proven R1 single-kernel version ----------------
template <int BLOCK>
__global__ void __launch_bounds__(BLOCK) voxel_sampler_fallback(
    const float* __restrict__ pts, const float* __restrict__ boxes,
    float* __restrict__ out, int N, int S) {
  constexpr int NW = BLOCK / 64;
  const int b = blockIdx.x;
  const int tid = threadIdx.x;
  const int lane = tid & 63;
  const int wid = tid >> 6;

  const float cx = boxes[b * 7 + 0];
  const float cy = boxes[b * 7 + 1];
  const float hdx = __fmul_rn(boxes[b * 7 + 3], 0.5f);
  const float hdy = __fmul_rn(boxes[b * 7 + 4], 0.5f);
  const float r = __fmul_rn(
      __fsqrt_rn(__fadd_rn(__fmul_rn(hdx, hdx), __fmul_rn(hdy, hdy))),
      GAMMA_F);

  __shared__ int s_wsum[NW];
  __shared__ int s_count;
  if (tid == 0) s_count = 0;
  __syncthreads();

  float* outb = out + (size_t)b * S * F_DIM;

  for (int base = 0; base < N; base += BLOCK) {
    const int i = base + tid;
    bool sel = false;
    float x = 0.0f, y = 0.0f;
    if (i < N) {
      x = pts[i * F_DIM + 0];
      y = pts[i * F_DIM + 1];
      const float ddx = __fsub_rn(x, cx);
      const float ddy = __fsub_rn(y, cy);
      const float dis =
          __fsqrt_rn(__fadd_rn(__fmul_rn(ddx, ddx), __fmul_rn(ddy, ddy)));
      sel = (dis <= r);
    }
    const unsigned long long m = __ballot(sel);
    if (lane == 0) s_wsum[wid] = __popcll(m);
    __syncthreads();
    const int cbase = s_count;
    int wbase = 0;
    int tot = 0;
#pragma unroll
    for (int w = 0; w < NW; ++w) {
      const int v = s_wsum[w];
      if (w < wid) wbase += v;
      tot += v;
    }
    const int pos = cbase + wbase + __popcll(m & ((1ULL << lane) - 1ULL));
    if (sel && pos < S) {
      float* o = outb + pos * F_DIM;
      o[0] = x;
      o[1] = y;
      o[2] = pts[i * F_DIM + 2];
      o[3] = pts[i * F_DIM + 3];
      o[4] = pts[i * F_DIM + 4];
    }
    __syncthreads();
    if (tid == 0) s_count = cbase + tot;
    __syncthreads();
    if (cbase + tot >= S) break;
  }

  __syncthreads();
  int cnt = s_count;
  if (cnt > S) cnt = S;
  for (int j = cnt * F_DIM + tid; j < S * F_DIM; j += BLOCK) outb[j] = 0.0f;
}

extern "C" void kernel_launch(void* const* d_in, const int* in_sizes, int n_in,
                              void* d_out, int out_size, void* d_ws,
                              size_t ws_size, hipStream_t stream) {
  const float* pts = (const float*)d_in[0];
  const float* boxes = (const float*)d_in[1];
  float* out = (float*)d_out;

  const int N = in_sizes[0] / F_DIM;     // 200000
  const int B = in_sizes[1] / 7;         // 256
  const int S = out_size / (B * F_DIM);  // 128

  const int NSEG = 256;
  int L = ((N + NSEG - 1) / NSEG + 1) & ~1;  // even
  const int NGRP = B / BOXG;                 // 32
  constexpr int NWAVE = 8;                   // 512-thread blocks

  const size_t sz_cnt = (size_t)B * NSEG * sizeof(int);
  const size_t off_idx = (sz_cnt + 255) & ~(size_t)255;
  const size_t sz_idx = (size_t)B * NSEG * S * sizeof(unsigned short);
  const size_t need = off_idx + sz_idx;

  const bool fast = (ws_size >= need) && (L >= 2) && (L <= MAXL) &&
                    (L - 1 <= 65535) && (B % BOXG == 0) && (S <= 256) &&
                    (NSEG <= MAX_NSEG) && (NGRP % NWAVE == 0) &&
                    ((size_t)L * NSEG >= (size_t)N);

  if (fast) {
    char* ws = (char*)d_ws;
    int* cnt = (int*)ws;
    unsigned short* idx = (unsigned short*)(ws + off_idx);

    const int bpg = NGRP / NWAVE;  // 4
    seg_lds_kernel<NWAVE><<<NSEG * bpg, NWAVE * 64, 0, stream>>>(
        pts, boxes, cnt, idx, N, S, NSEG, L, NGRP);
    gather_kernel<<<B, 256, 0, stream>>>(pts, cnt, idx, out, N, S, NSEG, L);
  } else {
    voxel_sampler_fallback<1024><<<B, 1024, 0, stream>>>(pts, boxes, out, N,
                                                         S);
  }
}